// Round 10
// baseline (247.603 us; speedup 1.0000x reference)
//
#include <hip/hip_runtime.h>
#include <math.h>

// GCN 2-layer forward on MI355X — round 10:
//  * deg accumulated via 4-way-replicated float atomics in the rank pass
//    (hidden under gemm1); dinv finalized inside scan1 -> k_deg gone
//  * scan1's last block computes the 49-wide top-level exclusive scan
//    (pp_s); consumers add pp_s[node>>10] -> k_scan3 gone
//  * 8 dispatches total (was 10)
#define CH   128
#define CH4  32
#define TPB  256
#define SCANB 1024
#define WIMG 16384       // shorts per (layer,colh) fragment image (32 KB)
#define NREP 4

typedef __attribute__((ext_vector_type(8))) short short8;   // 8 bf16 (4 VGPRs)
typedef __attribute__((ext_vector_type(4))) float floatx4;  // MFMA acc

// round-to-nearest-even fp32 -> bf16 (bit pattern)
static __device__ __forceinline__ unsigned short f2bf(float f) {
    unsigned u = __float_as_uint(f);
    return (unsigned short)((u + 0x7fffu + ((u >> 16) & 1u)) >> 16);
}
static __device__ __forceinline__ float bf2f(unsigned short s) {
    return __uint_as_float(((unsigned)s) << 16);
}
static __device__ __forceinline__ float4 bf4_to_f4(ushort4 u) {
    return make_float4(bf2f(u.x), bf2f(u.y), bf2f(u.z), bf2f(u.w));
}

// ---------------------------------------------------------------------------
// k_prep: split W1,W2 into bf16 hi/lo B-fragment images (32 KB per colh).
// ---------------------------------------------------------------------------
__global__ void k_prep(const float* __restrict__ W1, const float* __restrict__ W2,
                       short* __restrict__ Wsplit) {
    int i = blockIdx.x * blockDim.x + threadIdx.x;   // over 2*128*128
    if (i >= 2 * CH * CH) return;
    int layer = i >> 14;
    int idx   = i & 16383;
    int k = idx >> 7, c = idx & 127;
    float w = (layer ? W2 : W1)[k * CH + c];
    unsigned short hi = f2bf(w);
    unsigned short lo = f2bf(w - bf2f(hi));
    int colh = c >> 6, nn = c & 63;
    int kt = k >> 5, q = (k & 31) >> 3, j = k & 7;
    int ns = nn >> 4, ln = q * 16 + (nn & 15);
    size_t base = (size_t)(layer * 2 + colh) * WIMG;
    size_t off  = ((size_t)(kt * 4 + ns) * 64 + ln) * 8 + j;
    Wsplit[base + off]        = (short)hi;
    Wsplit[base + 8192 + off] = (short)lo;
}

// contiguous 32 KB stage of the pre-split fragment image
#define STAGE_W(sW, Wfrag, tid)                                    \
    {                                                              \
        const float4* gsrc = (const float4*)(Wfrag);               \
        float4* ldst = (float4*)(sW);                              \
        _Pragma("unroll")                                          \
        for (int i = 0; i < 8; ++i)                                \
            ldst[i * TPB + (tid)] = gsrc[i * TPB + (tid)];         \
    }

// ---------------------------------------------------------------------------
// fp32-input MFMA GEMM body (3-term Markidis split), bf16 output.
// Frag layouts (m89/m91/m120-verified):
//   A: m=lane&15, k=(lane>>4)*8+j ; B mirrored ; D: col=lane&15, row=(lane>>4)*4+reg
// ---------------------------------------------------------------------------
static __device__ __forceinline__ void gemm_body_f32(
        const float* __restrict__ X, const short* __restrict__ Wfrag,
        unsigned short* __restrict__ H, int n, int tile, int colh, int tid) {
    __shared__ __align__(16) short sW[2][4][4][64][8];   // 32 KB
    STAGE_W(sW, Wfrag, tid);
    __syncthreads();

    const int lane = tid & 63;
    const int wv   = tid >> 6;
    const int q    = lane >> 4;
    const int m    = lane & 15;
    const int row0 = tile * 64 + wv * 16;
    if (row0 >= n) return;

    int rrow = row0 + m;
    if (rrow > n - 1) rrow = n - 1;

    const float4* xr = (const float4*)(X + (size_t)rrow * CH);
    float4 xa[4][2];
    #pragma unroll
    for (int kt = 0; kt < 4; ++kt) {
        xa[kt][0] = xr[kt * 8 + q * 2 + 0];
        xa[kt][1] = xr[kt * 8 + q * 2 + 1];
    }

    floatx4 acc[4];
    #pragma unroll
    for (int ns = 0; ns < 4; ++ns) acc[ns] = (floatx4){0.f, 0.f, 0.f, 0.f};

    #pragma unroll
    for (int kt = 0; kt < 4; ++kt) {
        float xf[8] = { xa[kt][0].x, xa[kt][0].y, xa[kt][0].z, xa[kt][0].w,
                        xa[kt][1].x, xa[kt][1].y, xa[kt][1].z, xa[kt][1].w };
        short8 ah, al;
        #pragma unroll
        for (int j = 0; j < 8; ++j) {
            float v = xf[j];
            unsigned short h = f2bf(v);
            ah[j] = (short)h;
            al[j] = (short)f2bf(v - bf2f(h));
        }
        #pragma unroll
        for (int ns = 0; ns < 4; ++ns) {
            short8 bh = *(const short8*)&sW[0][kt][ns][lane][0];
            short8 bl = *(const short8*)&sW[1][kt][ns][lane][0];
            acc[ns] = __builtin_amdgcn_mfma_f32_16x16x32_bf16(ah, bh, acc[ns], 0, 0, 0);
            acc[ns] = __builtin_amdgcn_mfma_f32_16x16x32_bf16(al, bh, acc[ns], 0, 0, 0);
            acc[ns] = __builtin_amdgcn_mfma_f32_16x16x32_bf16(ah, bl, acc[ns], 0, 0, 0);
        }
    }

    #pragma unroll
    for (int ns = 0; ns < 4; ++ns) {
        #pragma unroll
        for (int reg = 0; reg < 4; ++reg) {
            int r = row0 + q * 4 + reg;
            if (r < n)
                H[(size_t)r * CH + colh * 64 + ns * 16 + m] = f2bf(acc[ns][reg]);
        }
    }
}

// bf16-input variant: A is exact bf16 -> 2 MFMAs per fragment.
static __device__ __forceinline__ void gemm_body_bf(
        const unsigned short* __restrict__ X, const short* __restrict__ Wfrag,
        unsigned short* __restrict__ H, int n, int tile, int colh, int tid) {
    __shared__ __align__(16) short sW[2][4][4][64][8];   // 32 KB
    STAGE_W(sW, Wfrag, tid);
    __syncthreads();

    const int lane = tid & 63;
    const int wv   = tid >> 6;
    const int q    = lane >> 4;
    const int m    = lane & 15;
    const int row0 = tile * 64 + wv * 16;
    if (row0 >= n) return;

    int rrow = row0 + m;
    if (rrow > n - 1) rrow = n - 1;

    const short8* xr8 = (const short8*)(X + (size_t)rrow * CH);  // 16 per row
    short8 a[4];
    #pragma unroll
    for (int kt = 0; kt < 4; ++kt) a[kt] = xr8[kt * 4 + q];      // 16 B load

    floatx4 acc[4];
    #pragma unroll
    for (int ns = 0; ns < 4; ++ns) acc[ns] = (floatx4){0.f, 0.f, 0.f, 0.f};

    #pragma unroll
    for (int kt = 0; kt < 4; ++kt) {
        #pragma unroll
        for (int ns = 0; ns < 4; ++ns) {
            short8 bh = *(const short8*)&sW[0][kt][ns][lane][0];
            short8 bl = *(const short8*)&sW[1][kt][ns][lane][0];
            acc[ns] = __builtin_amdgcn_mfma_f32_16x16x32_bf16(a[kt], bh, acc[ns], 0, 0, 0);
            acc[ns] = __builtin_amdgcn_mfma_f32_16x16x32_bf16(a[kt], bl, acc[ns], 0, 0, 0);
        }
    }

    #pragma unroll
    for (int ns = 0; ns < 4; ++ns) {
        #pragma unroll
        for (int reg = 0; reg < 4; ++reg) {
            int r = row0 + q * 4 + reg;
            if (r < n)
                H[(size_t)r * CH + colh * 64 + ns * 16 + m] = f2bf(acc[ns][reg]);
        }
    }
}

// fused: blocks [0, nbE): per-edge replicated rank atomic + replicated float
// deg atomic (long pole, dispatched first); blocks [nbE, ...): gemm1.
__global__ __launch_bounds__(TPB, 4)
void k_gemm_rank(const float* __restrict__ X, const short* __restrict__ Wsplit,
                 unsigned short* __restrict__ H, int n,
                 const int* __restrict__ dst, const float* __restrict__ ew,
                 int* __restrict__ counts_rep, float* __restrict__ deg_rep,
                 int* __restrict__ rank, int E, int nbE, int Np) {
    int bx = blockIdx.x;
    if (bx < nbE) {
        int e = bx * TPB + threadIdx.x;
        if (e < E) {
            int d = dst[e];
            if ((unsigned)d < (unsigned)n) {
                int rep = e & (NREP - 1);
                rank[e] = atomicAdd(&counts_rep[rep * Np + d], 1);
                unsafeAtomicAdd(&deg_rep[rep * Np + d], ew[e]);
            }
        }
    } else {
        bx -= nbE;
        int colh = bx & 1;
        gemm_body_f32(X, Wsplit + (size_t)colh * WIMG, H, n, bx >> 1, colh,
                      threadIdx.x);
    }
}

__global__ __launch_bounds__(TPB, 4)
void k_gemm_bf(const unsigned short* __restrict__ X, const short* __restrict__ Wsplit,
               unsigned short* __restrict__ H, int n) {
    int colh = (int)blockIdx.x & 1;
    gemm_body_bf(X, Wsplit + (size_t)colh * WIMG, H, n,
                 (int)blockIdx.x >> 1, colh, threadIdx.x);
}

// ---------------------------------------------------------------------------
// scan1: sum replica counts -> counts_tot, block-local exclusive scan ->
// row_start (LOCAL), replica offsets, dinv = rsqrt(1 + sum deg_rep).
// Last-finishing block top-scans the <=64 partials into pp_s (exclusive).
// Consumers compute absolute base = row_start[i] + pp_s[i >> 10].
// ---------------------------------------------------------------------------
__global__ __launch_bounds__(SCANB)
void k_scan1(const int* __restrict__ counts_rep, const float* __restrict__ deg_rep,
             int Np, int* __restrict__ counts_tot, int4* __restrict__ repoff,
             int* __restrict__ row_start, float* __restrict__ dinv,
             int* __restrict__ partials, int* __restrict__ pp_s,
             int* __restrict__ done, int nb, int n) {
    __shared__ int s[SCANB];
    __shared__ int slast;
    int gid = blockIdx.x * SCANB + threadIdx.x;
    int c0 = 0, c1 = 0, c2 = 0, c3 = 0;
    if (gid < n) {
        c0 = counts_rep[gid];
        c1 = counts_rep[Np + gid];
        c2 = counts_rep[2 * Np + gid];
        c3 = counts_rep[3 * Np + gid];
        float dsum = 1.0f + deg_rep[gid] + deg_rep[Np + gid]
                   + deg_rep[2 * Np + gid] + deg_rep[3 * Np + gid];
        dinv[gid] = rsqrtf(dsum);
    }
    int v = c0 + c1 + c2 + c3;
    s[threadIdx.x] = v;
    __syncthreads();
    for (int off = 1; off < SCANB; off <<= 1) {
        int t = (threadIdx.x >= off) ? s[threadIdx.x - off] : 0;
        __syncthreads();
        s[threadIdx.x] += t;
        __syncthreads();
    }
    if (gid < n) {
        row_start[gid]  = s[threadIdx.x] - v;   // block-local exclusive
        counts_tot[gid] = v;
        repoff[gid]     = make_int4(0, c0, c0 + c1, c0 + c1 + c2);
    }
    if (threadIdx.x == SCANB - 1) {
        partials[blockIdx.x] = s[SCANB - 1];
        __threadfence();
        int old = atomicAdd(done, 1);
        slast = (old == nb - 1);
    }
    __syncthreads();
    if (slast && threadIdx.x < 64) {
        // device-coherent read of all partials, then 64-lane exclusive scan
        int pv = (threadIdx.x < nb) ? atomicAdd(&partials[threadIdx.x], 0) : 0;
        int inc = pv;
        #pragma unroll
        for (int off = 1; off < 64; off <<= 1) {
            int t = __shfl_up(inc, off, 64);
            if ((threadIdx.x & 63) >= off) inc += t;
        }
        if (threadIdx.x < nb) pp_s[threadIdx.x] = inc - pv;
    }
}

// atomic-free fill: edges[row_start[d]+pp_s[d>>10]+repoff[rep]+rank[e]] = {src, ew}
__global__ void k_fill(const int* __restrict__ src, const int* __restrict__ dst,
                       const float* __restrict__ ew, const int* __restrict__ row_start,
                       const int* __restrict__ pp_s, const int4* __restrict__ repoff,
                       const int* __restrict__ rank, int2* __restrict__ edges,
                       int E, int n) {
    int e = blockIdx.x * blockDim.x + threadIdx.x;
    if (e >= E) return;
    int s = src[e], d = dst[e];
    if ((unsigned)s >= (unsigned)n || (unsigned)d >= (unsigned)n) return;
    int rep = e & (NREP - 1);
    int4 ro = repoff[d];
    int roa[4] = {ro.x, ro.y, ro.z, ro.w};
    int base = row_start[d] + pp_s[d >> 10];
    edges[base + roa[rep] + rank[e]] = make_int2(s, __float_as_int(ew[e]));
}

// ---------------------------------------------------------------------------
// CSR aggregate over bf16 h:
//   out[i] = (relu?)( h[i]*di^2 + bias + di * sum_j w'_j * h[s_j] )
// FIXUP=1: w' = raw_ew * dinv[src], written back. OUT_BF16: store bf16.
// ---------------------------------------------------------------------------
template<int RELU_OUT, int FIXUP, int OUT_BF16>
__global__ __launch_bounds__(TPB)
void k_aggregate(const unsigned short* __restrict__ h, const int* __restrict__ row_start,
                 const int* __restrict__ pp_s, const int* __restrict__ counts,
                 int2* __restrict__ edges, const float* __restrict__ dinv,
                 const float* __restrict__ bias, void* __restrict__ out, int n) {
    int t = blockIdx.x * blockDim.x + threadIdx.x;
    int node = t >> 5;
    if (node >= n) return;
    int tx = t & 31;

    const ushort4* h4 = (const ushort4*)h;
    float di = dinv[node];
    float4 b  = ((const float4*)bias)[tx];
    float4 hv = bf4_to_f4(h4[(size_t)node * CH4 + tx]);
    float4 acc = make_float4(0.f, 0.f, 0.f, 0.f);

    int j   = row_start[node] + pp_s[node >> 10];
    int end = j + counts[node];

    for (; j + 8 <= end; j += 8) {
        int2 e[8];
        #pragma unroll
        for (int i = 0; i < 8; ++i) e[i] = edges[j + i];
        ushort4 g[8];
        #pragma unroll
        for (int i = 0; i < 8; ++i) g[i] = h4[(size_t)e[i].x * CH4 + tx];
        float w[8];
        #pragma unroll
        for (int i = 0; i < 8; ++i) {
            w[i] = __int_as_float(e[i].y);
            if (FIXUP) w[i] *= dinv[e[i].x];
        }
        if (FIXUP && tx == 0) {
            #pragma unroll
            for (int i = 0; i < 8; ++i) edges[j + i].y = __float_as_int(w[i]);
        }
        #pragma unroll
        for (int i = 0; i < 8; ++i) {
            float4 gf = bf4_to_f4(g[i]);
            acc.x += gf.x * w[i]; acc.y += gf.y * w[i];
            acc.z += gf.z * w[i]; acc.w += gf.w * w[i];
        }
    }
    if (j + 4 <= end) {
        int2 e[4];
        #pragma unroll
        for (int i = 0; i < 4; ++i) e[i] = edges[j + i];
        ushort4 g[4];
        #pragma unroll
        for (int i = 0; i < 4; ++i) g[i] = h4[(size_t)e[i].x * CH4 + tx];
        float w[4];
        #pragma unroll
        for (int i = 0; i < 4; ++i) {
            w[i] = __int_as_float(e[i].y);
            if (FIXUP) w[i] *= dinv[e[i].x];
        }
        if (FIXUP && tx == 0) {
            #pragma unroll
            for (int i = 0; i < 4; ++i) edges[j + i].y = __float_as_int(w[i]);
        }
        #pragma unroll
        for (int i = 0; i < 4; ++i) {
            float4 gf = bf4_to_f4(g[i]);
            acc.x += gf.x * w[i]; acc.y += gf.y * w[i];
            acc.z += gf.z * w[i]; acc.w += gf.w * w[i];
        }
        j += 4;
    }
    for (; j < end; ++j) {
        int2 e0 = edges[j];
        float w0 = __int_as_float(e0.y);
        if (FIXUP) w0 *= dinv[e0.x];
        if (FIXUP && tx == 0) edges[j].y = __float_as_int(w0);
        float4 gf = bf4_to_f4(h4[(size_t)e0.x * CH4 + tx]);
        acc.x += gf.x * w0; acc.y += gf.y * w0;
        acc.z += gf.z * w0; acc.w += gf.w * w0;
    }

    float sc = di * di;
    float4 o = make_float4(hv.x * sc + b.x + di * acc.x,
                           hv.y * sc + b.y + di * acc.y,
                           hv.z * sc + b.z + di * acc.z,
                           hv.w * sc + b.w + di * acc.w);
    if (RELU_OUT) {
        o.x = fmaxf(o.x, 0.f); o.y = fmaxf(o.y, 0.f);
        o.z = fmaxf(o.z, 0.f); o.w = fmaxf(o.w, 0.f);
    }
    if (OUT_BF16) {
        ushort4 u = make_ushort4(f2bf(o.x), f2bf(o.y), f2bf(o.z), f2bf(o.w));
        ((ushort4*)out)[(size_t)node * CH4 + tx] = u;
    } else {
        ((float4*)out)[(size_t)node * CH4 + tx] = o;
    }
}

// ---------------------------------------------------------------------------
extern "C" void kernel_launch(void* const* d_in, const int* in_sizes, int n_in,
                              void* d_out, int out_size, void* d_ws, size_t ws_size,
                              hipStream_t stream) {
    const float* x  = (const float*)d_in[0];   // [N,128]
    const int*   ei = (const int*)d_in[1];     // [2,E]
    const float* ew = (const float*)d_in[2];   // [E]
    const float* W1 = (const float*)d_in[3];
    const float* b1 = (const float*)d_in[4];
    const float* W2 = (const float*)d_in[5];
    const float* b2 = (const float*)d_in[6];
    float* out = (float*)d_out;                // [N,128]

    const int N = in_sizes[0] / CH;
    const int E = in_sizes[2];
    const int* src = ei;
    const int* dst = ei + E;

    // workspace layout (16B-aligned)
    size_t Np = ((size_t)N + 255) & ~(size_t)255;
    size_t Ep = ((size_t)E + 63) & ~(size_t)63;
    float* ws          = (float*)d_ws;
    float* dinv        = ws;                                // Np floats
    unsigned short* h  = (unsigned short*)(dinv + Np);      // N*CH bf16
    unsigned short* o1 = h + (size_t)N * CH;                // N*CH bf16
    // ---- contiguous zero region ----
    int*   counts_rep  = (int*)(o1 + (size_t)N * CH);       // NREP*Np ints
    float* deg_rep     = (float*)(counts_rep + NREP * Np);  // NREP*Np floats
    int*   done        = (int*)(deg_rep + NREP * Np);       // 64 ints (1 used)
    size_t zero_bytes  = (size_t)(2 * NREP) * Np * 4 + 256;
    // ---- rest ----
    int*  counts_tot   = done + 64;                         // Np ints
    int*  row_start    = counts_tot + Np;                   // Np ints
    int4* repoff       = (int4*)(row_start + Np);           // Np int4
    int*  rank         = (int*)(repoff + Np);               // Ep ints
    int*  partials     = rank + Ep;                         // 64 ints
    int*  pp_s         = partials + 64;                     // 64 ints
    int2* edges        = (int2*)(pp_s + 64);                // E int2
    short* Wsplit      = (short*)(edges + E);               // 4*WIMG shorts

    const int nbE    = (E + TPB - 1) / TPB;
    const int nbAgg  = (int)(((size_t)N * 32 + TPB - 1) / TPB);
    const int nbScan = (N + SCANB - 1) / SCANB;     // 49 <= 64
    const int nbGemm2 = 2 * ((N + 63) / 64);
    const int nbPrep  = (2 * CH * CH + TPB - 1) / TPB;

    // ---- prep: zero counters/deg/done, split W ----
    hipMemsetAsync(counts_rep, 0, zero_bytes, stream);
    k_prep     <<<nbPrep, TPB, 0, stream>>>(W1, W2, Wsplit);

    // ---- fused: replicated rank+deg pass | gemm1 (h = x@W1, bf16) ----
    k_gemm_rank<<<nbE + nbGemm2, TPB, 0, stream>>>(x, Wsplit, h, N, dst, ew,
                                                   counts_rep, deg_rep, rank,
                                                   E, nbE, (int)Np);
    // ---- CSR finalize: one scan kernel (last block does the top scan) ----
    k_scan1    <<<nbScan, SCANB, 0, stream>>>(counts_rep, deg_rep, (int)Np,
                                              counts_tot, repoff, row_start,
                                              dinv, partials, pp_s, done,
                                              nbScan, N);
    k_fill     <<<nbE, TPB, 0, stream>>>(src, dst, ew, row_start, pp_s, repoff,
                                         rank, edges, E, N);

    // ---- layer 1 aggregate: o1 = relu(agg(h)) in bf16; stores w' ----
    k_aggregate<1,1,1><<<nbAgg, TPB, 0, stream>>>(h, row_start, pp_s, counts_tot,
                                                  edges, dinv, b1, o1, N);
    // ---- layer 2 ----
    k_gemm_bf         <<<nbGemm2, TPB, 0, stream>>>(o1, Wsplit + 2 * WIMG, h, N);
    k_aggregate<1,0,0><<<nbAgg, TPB, 0, stream>>>(h, row_start, pp_s, counts_tot,
                                                  edges, dinv, b2, out, N);
}